// Round 3
// baseline (205.456 us; speedup 1.0000x reference)
//
#include <hip/hip_runtime.h>

typedef unsigned short u16;
typedef unsigned int   u32;
typedef __attribute__((ext_vector_type(4))) float f32x4;
typedef __attribute__((ext_vector_type(8))) short bf16x8;
typedef __attribute__((ext_vector_type(8))) unsigned short u16x8;
typedef __attribute__((ext_vector_type(4))) unsigned short u16x4;

#define MROWS 4096
#define DDIM  1024

__device__ __forceinline__ u16 f2bf(float f) {
  u32 u = __float_as_uint(f);
  return (u16)((u + 0x7FFFu + ((u >> 16) & 1u)) >> 16);   // RNE
}
__device__ __forceinline__ float bf2f(u16 h) { return __uint_as_float(((u32)h) << 16); }

// ---------- JAX partitionable threefry2x32, key(42): bits(n) = o0^o1 ----------
__device__ __forceinline__ u32 rotl32(u32 x, int r) { return (x << r) | (x >> (32 - r)); }
__device__ __forceinline__ u32 threefry_bits(u32 n) {
  const u32 K0 = 0u, K1 = 42u, K2 = 0x1BD11BDAu ^ 0u ^ 42u;
  u32 x0 = K0;
  u32 x1 = n + K1;
#define TF4(a,b,c,d) \
  x0 += x1; x1 = rotl32(x1, a); x1 ^= x0; \
  x0 += x1; x1 = rotl32(x1, b); x1 ^= x0; \
  x0 += x1; x1 = rotl32(x1, c); x1 ^= x0; \
  x0 += x1; x1 = rotl32(x1, d); x1 ^= x0;
  TF4(13,15,26,6);  x0 += K1; x1 += K2 + 1u;
  TF4(17,29,16,24); x0 += K2; x1 += K0 + 2u;
  TF4(13,15,26,6);  x0 += K0; x1 += K1 + 3u;
  TF4(17,29,16,24); x0 += K1; x1 += K2 + 4u;
  TF4(13,15,26,6);  x0 += K2; x1 += K0 + 5u;
#undef TF4
  return x0 ^ x1;
}

// ============ expand: 3-term hi/lo split + fused dropout-mask generation ============
// element e -> slots [3e..3e+2]: A-pattern [ah,ah,al], B-pattern [bh,bl,bh]
__global__ __launch_bounds__(256)
void expand3(const float4* __restrict__ x, u16* __restrict__ out, float scale, int patA,
             u32* __restrict__ mask, u32 wordBase, u32 nWords) {
  int t = blockIdx.x * 256 + threadIdx.x;      // 524288 threads, 8 floats each
  float4 v0 = x[(size_t)t * 2], v1 = x[(size_t)t * 2 + 1];
  float vv[8] = {v0.x*scale, v0.y*scale, v0.z*scale, v0.w*scale,
                 v1.x*scale, v1.y*scale, v1.z*scale, v1.w*scale};
  u16 o[24];
#pragma unroll
  for (int j = 0; j < 8; ++j) {
    u16 h = f2bf(vv[j]);
    u16 l = f2bf(vv[j] - bf2f(h));             // Sterbenz-exact residual, RNE
    if (patA) { o[3*j]=h; o[3*j+1]=h; o[3*j+2]=l; }
    else      { o[3*j]=h; o[3*j+1]=l; o[3*j+2]=h; }
  }
  u16x8* dst = (u16x8*)(out + (size_t)t * 24);
#pragma unroll
  for (int q = 0; q < 3; ++q) {
    u16x8 wv;
#pragma unroll
    for (int j = 0; j < 8; ++j) wv[j] = o[q*8+j];
    dst[q] = wv;
  }
  // fused mask-gen: bit b of word w = MSB of threefry(w*32+b)  (1 = drop)
  if ((u32)t < nWords) {
    u32 wi = wordBase + (u32)t;
    u32 n0 = wi * 32u;
    u32 wbits = 0;
#pragma unroll 4
    for (int b = 0; b < 32; ++b) wbits |= (threefry_bits(n0 + (u32)b) >> 31) << b;
    mask[wi] = wbits;
  }
}

// ============ V transpose to bf16: VT[d][k] = bf16(x2[k][d]) ============
__global__ __launch_bounds__(256)
void transpose_bf16(const float* __restrict__ x2, u16* __restrict__ VT) {
  __shared__ float tile[64][65];
  int tid = threadIdx.x;
  int dt = blockIdx.x;   // 16 D-tiles
  int kt = blockIdx.y;   // 64 K-tiles
#pragma unroll
  for (int it = 0; it < 16; ++it) {
    int lin = it * 256 + tid;
    int r = lin >> 6, c = lin & 63;
    tile[r][c] = x2[(size_t)(kt*64 + r) * DDIM + dt*64 + c];
  }
  __syncthreads();
#pragma unroll
  for (int it = 0; it < 16; ++it) {
    int lin = it * 256 + tid;
    int dr = lin >> 6, kc = lin & 63;
    VT[(size_t)(dt*64 + dr) * MROWS + kt*64 + kc] = f2bf(tile[kc][dr]);
  }
}

// ============ 256x256 8-phase GEMM: C[M,N] = A[M,K] * Bt[N,K]^T ============
// 512 thr (8 waves 2Mx4N), BK=64, dbuf LDS 128KB, chunk-XOR swizzle, XCD swizzle,
// kx-split phases (8/8/4/4 ds_reads), counted vmcnt(6), setprio on MFMA.
__device__ __forceinline__ void gload16(const u16* g, u16* l) {
  __builtin_amdgcn_global_load_lds(
      (const __attribute__((address_space(1))) void*)g,
      (__attribute__((address_space(3))) void*)l, 16, 0, 0);
}

#define BARRIER() do { asm volatile("" ::: "memory"); __builtin_amdgcn_s_barrier(); \
                       asm volatile("" ::: "memory"); } while (0)
#define LGKM0()   do { asm volatile("s_waitcnt lgkmcnt(0)" ::: "memory"); \
                       __builtin_amdgcn_sched_barrier(0); } while (0)
#define VMCNT6()  do { asm volatile("s_waitcnt vmcnt(6)" ::: "memory"); } while (0)

__device__ __forceinline__ void mma4x4(f32x4 (&accq)[4][4], const bf16x8 (&a)[4],
                                       const bf16x8 (&b)[4]) {
#pragma unroll
  for (int m = 0; m < 4; ++m)
#pragma unroll
    for (int n = 0; n < 4; ++n)
      accq[m][n] = __builtin_amdgcn_mfma_f32_16x16x32_bf16(a[m], b[n], accq[m][n], 0, 0, 0);
}

// LDS u16 layout: A(d,h) = (d*2+h)*8192 ; B(d,h) = 32768 + (d*2+h)*8192
__global__ __launch_bounds__(512, 2)
void gemm256(const u16* __restrict__ A, const u16* __restrict__ Bt, float* __restrict__ C,
             int M, int N, int K, int ntpc) {
  __shared__ u16 smem[65536];   // 128 KiB
  const int tid = threadIdx.x;
  const int lane = tid & 63;
  const int w = tid >> 6;
  const int wr = w >> 2;          // 0..1
  const int wc = w & 3;           // 0..3
  const int fr = lane & 15;
  const int hi = lane >> 4;

  // XCD-chunked bijective swizzle (nbxy % 8 == 0 for all our grids)
  const int nbxy = gridDim.x * gridDim.y;
  const int id0 = blockIdx.y * gridDim.x + blockIdx.x;
  const int id  = (id0 & 7) * (nbxy >> 3) + (id0 >> 3);
  const int bxi = id % gridDim.x;
  const int byi = id / gridDim.x;

  const long bm = (long)byi * 256;
  const long bn = (long)bxi * 256;
  const size_t kcol0 = (size_t)blockIdx.z * ntpc * 64;
  float* Cz = C + (size_t)blockIdx.z * (size_t)M * N;

  // staging: thread -> (row=tid>>3, chunk=tid&7); global src chunk pre-swizzled
  const int srow = tid >> 3;
  const int scol = (((tid & 7) ^ (srow & 7)) << 3);
  const u16* Abase = A  + (size_t)(bm + srow) * K + kcol0 + scol;
  const u16* Bbase = Bt + (size_t)(bn + srow) * K + kcol0 + scol;

  // swizzled read chunk offsets (u16 units); rows ≡ fr (mod 8) for all frags
  const int csw0 = ((hi)     ^ (fr & 7)) << 3;
  const int csw1 = ((4 + hi) ^ (fr & 7)) << 3;
  const int arow = (wr*16 + fr) * 64;   // + m*2048 per m-frag
  const int brow = (wc*16 + fr) * 64;   // + (n&1)*4096, half = n>>1

#define RD_A(dst, D, H, CSW) do { \
    const u16* _b = smem + ((D)*2+(H))*8192 + arow + (CSW); \
    dst[0] = *(const bf16x8*)(_b); \
    dst[1] = *(const bf16x8*)(_b + 2048); \
    dst[2] = *(const bf16x8*)(_b + 4096); \
    dst[3] = *(const bf16x8*)(_b + 6144); } while (0)
#define RD_B(dst, D, CSW) do { \
    const u16* _b0 = smem + 32768 + ((D)*2+0)*8192 + brow + (CSW); \
    const u16* _b1 = smem + 32768 + ((D)*2+1)*8192 + brow + (CSW); \
    dst[0] = *(const bf16x8*)(_b0); \
    dst[1] = *(const bf16x8*)(_b0 + 4096); \
    dst[2] = *(const bf16x8*)(_b1); \
    dst[3] = *(const bf16x8*)(_b1 + 4096); } while (0)

  f32x4 accL[4][4], accH[4][4];
#pragma unroll
  for (int m = 0; m < 4; ++m)
#pragma unroll
    for (int n = 0; n < 4; ++n) {
      accL[m][n] = (f32x4){0.f, 0.f, 0.f, 0.f};
      accH[m][n] = (f32x4){0.f, 0.f, 0.f, 0.f};
    }
  bf16x8 aE[4], aO[4], bE[4], bO[4];

#define STAGE_A(TAU,H,D) do { \
    const u16* _s = Abase + (size_t)(H)*128*K + (size_t)(TAU)*64; \
    u16* _d = smem + ((D)*2+(H))*8192 + tid*8; \
    gload16(_s, _d); gload16(_s + (size_t)64*K, _d + 4096); } while (0)
#define STAGE_B(TAU,H,D) do { \
    const u16* _s = Bbase + (size_t)(H)*128*K + (size_t)(TAU)*64; \
    u16* _d = smem + 32768 + ((D)*2+(H))*8192 + tid*8; \
    gload16(_s, _d); gload16(_s + (size_t)64*K, _d + 4096); } while (0)

  // prologue: tile0 (4 halves, oldest 8 loads) + tile1 A0,B0,B1 (6 loads)
  STAGE_A(0,0,0); STAGE_B(0,0,0); STAGE_B(0,1,0); STAGE_A(0,1,0);
  STAGE_A(1,0,1); STAGE_B(1,0,1); STAGE_B(1,1,1);
  VMCNT6();                 // tile0 fully landed
  BARRIER();

  const int nt = ntpc;
  for (int T = 0; T < nt; T += 2) {
    const int t1 = T + 1;
    const int t2 = (T + 2 < nt) ? T + 2 : nt - 1;   // tail: dummy re-stage into dead regions
    const int t3 = (T + 3 < nt) ? T + 3 : nt - 1;

    // p1: kx0, M-half0, buf0  (reads 8)
    RD_A(aE, 0, 0, csw0);
    RD_B(bE, 0, csw0);
    STAGE_A(t1, 1, 1);                      // A1(T+1): region last read prev p7/p8
    BARRIER(); LGKM0();
    __builtin_amdgcn_s_setprio(1); mma4x4(accL, aE, bE); __builtin_amdgcn_s_setprio(0);
    BARRIER();
    // p2: kx1, M-half0  (reads 8)
    RD_A(aO, 0, 0, csw1);
    RD_B(bO, 0, csw1);
    BARRIER(); LGKM0();
    __builtin_amdgcn_s_setprio(1); mma4x4(accL, aO, bO); __builtin_amdgcn_s_setprio(0);
    BARRIER();
    // p3: kx0, M-half1  (reads 4; stage 6: buf0 A0/B0/B1 free after p2)
    RD_A(aE, 0, 1, csw0);
    STAGE_A(t2, 0, 0); STAGE_B(t2, 0, 0); STAGE_B(t2, 1, 0);
    BARRIER(); LGKM0();
    __builtin_amdgcn_s_setprio(1); mma4x4(accH, aE, bE); __builtin_amdgcn_s_setprio(0);
    BARRIER();
    // p4: kx1, M-half1  (reads 4)  [vmcnt(6): tile T+1 fully landed]
    RD_A(aO, 0, 1, csw1);
    VMCNT6();
    BARRIER(); LGKM0();
    __builtin_amdgcn_s_setprio(1); mma4x4(accH, aO, bO); __builtin_amdgcn_s_setprio(0);
    BARRIER();
    // p5: kx0, M-half0, buf1  (reads 8; stage: buf0 A1 free after p4)
    RD_A(aE, 1, 0, csw0);
    RD_B(bE, 1, csw0);
    STAGE_A(t2, 1, 0);
    BARRIER(); LGKM0();
    __builtin_amdgcn_s_setprio(1); mma4x4(accL, aE, bE); __builtin_amdgcn_s_setprio(0);
    BARRIER();
    // p6: kx1, M-half0  (reads 8)
    RD_A(aO, 1, 0, csw1);
    RD_B(bO, 1, csw1);
    BARRIER(); LGKM0();
    __builtin_amdgcn_s_setprio(1); mma4x4(accL, aO, bO); __builtin_amdgcn_s_setprio(0);
    BARRIER();
    // p7: kx0, M-half1  (reads 4; stage 6: buf1 A0/B0/B1 free after p6)
    RD_A(aE, 1, 1, csw0);
    STAGE_A(t3, 0, 1); STAGE_B(t3, 0, 1); STAGE_B(t3, 1, 1);
    BARRIER(); LGKM0();
    __builtin_amdgcn_s_setprio(1); mma4x4(accH, aE, bE); __builtin_amdgcn_s_setprio(0);
    BARRIER();
    // p8: kx1, M-half1  (reads 4)  [vmcnt(6): tile T+2 fully landed]
    RD_A(aO, 1, 1, csw1);
    VMCNT6();
    BARRIER(); LGKM0();
    __builtin_amdgcn_s_setprio(1); mma4x4(accH, aO, bO); __builtin_amdgcn_s_setprio(0);
    BARRIER();
  }
#undef STAGE_A
#undef STAGE_B
#undef RD_A
#undef RD_B

  // epilogue: C/D layout col=lane&15, row=(lane>>4)*4+reg  [verified]
#pragma unroll
  for (int m = 0; m < 4; ++m)
#pragma unroll
    for (int n = 0; n < 4; ++n) {
      size_t rowL = (size_t)(bm + m*32 + wr*16 + hi*4);
      size_t rowH = rowL + 128;
      size_t col  = (size_t)(bn + n*64 + wc*16 + fr);
#pragma unroll
      for (int r = 0; r < 4; ++r) {
        Cz[(rowL + r) * N + col] = accL[m][n][r];
        Cz[(rowH + r) * N + col] = accH[m][n][r];
      }
    }
}

// ============ softmax + precomputed dropout mask -> bf16 P ============
__global__ __launch_bounds__(256)
void softmax_dropout(const float* __restrict__ S, const u32* __restrict__ mask,
                     u16* __restrict__ P) {
  const int tid  = threadIdx.x;
  const int lane = tid & 63;
  const int w    = tid >> 6;
  const int row  = blockIdx.x * 4 + w;   // one row per wave
  const float4* Sr = (const float4*)(S + (size_t)row * MROWS);
  float4 v[16];
#pragma unroll
  for (int i = 0; i < 16; ++i) v[i] = Sr[i * 64 + lane];
  float m = -3.0e38f;
#pragma unroll
  for (int i = 0; i < 16; ++i)
    m = fmaxf(m, fmaxf(fmaxf(v[i].x, v[i].y), fmaxf(v[i].z, v[i].w)));
#pragma unroll
  for (int off = 32; off > 0; off >>= 1) m = fmaxf(m, __shfl_xor(m, off, 64));
  float s = 0.0f;
#pragma unroll
  for (int i = 0; i < 16; ++i) {
    v[i].x = __expf(v[i].x - m); v[i].y = __expf(v[i].y - m);
    v[i].z = __expf(v[i].z - m); v[i].w = __expf(v[i].w - m);
    s += v[i].x + v[i].y + v[i].z + v[i].w;
  }
#pragma unroll
  for (int off = 32; off > 0; off >>= 1) s += __shfl_xor(s, off, 64);
  const float inv = 2.0f / s;            // softmax normalize * 1/(1-p)
  u16* Pr = P + (size_t)row * MROWS;
  const u32* Mw = mask + (size_t)row * 128;
#pragma unroll
  for (int i = 0; i < 16; ++i) {
    int j0 = (i * 64 + lane) * 4;
    u32 word = Mw[j0 >> 5];
    int sh = j0 & 31;
    float e[4] = {v[i].x, v[i].y, v[i].z, v[i].w};
    u16x4 o;
#pragma unroll
    for (int c = 0; c < 4; ++c) {
      float val = ((word >> (sh + c)) & 1u) ? 0.0f : e[c] * inv;
      o[c] = f2bf(val);
    }
    *(u16x4*)(Pr + j0) = o;
  }
}

// ============ split-K reduction: out = sum of 4 partials ============
__global__ __launch_bounds__(256)
void reduce4(const float4* __restrict__ p, float4* __restrict__ out) {
  size_t i = (size_t)blockIdx.x * 256 + threadIdx.x;
  const size_t NP = (size_t)MROWS * DDIM / 4;
  float4 a = p[i], b = p[i + NP], c = p[i + 2*NP], d = p[i + 3*NP];
  float4 r;
  r.x = a.x + b.x + c.x + d.x;
  r.y = a.y + b.y + c.y + d.y;
  r.z = a.z + b.z + c.z + d.z;
  r.w = a.w + b.w + c.w + d.w;
  out[i] = r;
}

// ============ launch ============
extern "C" void kernel_launch(void* const* d_in, const int* in_sizes, int n_in,
                              void* d_out, int out_size, void* d_ws, size_t ws_size,
                              hipStream_t stream) {
  const float* x1 = (const float*)d_in[0];
  const float* x2 = (const float*)d_in[1];
  float* out = (float*)d_out;
  char* ws = (char*)d_ws;

  // ws layout (bytes):
  //   XA [0,24M) | XB [24M,48M) | VT [48M,56M) | S [56M,120M) | MASK [120M,122M)
  //   P (32M) overlays XA+XB after GEMM1 ; partials (64M) overlay S after softmax
  const size_t OFF_XB   = 25165824;
  const size_t OFF_VT   = 50331648;
  const size_t OFF_S    = 58720256;
  const size_t OFF_MASK = 125829120;
  const size_t NEED     = 127926272;
  if (ws_size < NEED) {
    hipMemsetAsync(d_out, 0x7F, (size_t)out_size * sizeof(float), stream);
    return;
  }
  u16*   XA = (u16*)(ws);
  u16*   XB = (u16*)(ws + OFF_XB);
  u16*   VT = (u16*)(ws + OFF_VT);
  float* S  = (float*)(ws + OFF_S);
  float* PT = (float*)(ws + OFF_S);     // partials reuse S
  u32*   MK = (u32*)(ws + OFF_MASK);
  u16*   P  = (u16*)(ws);               // reuses XA(+XB) region

  // total mask words = 4096*4096/32 = 524288; split across the two expand kernels
  expand3<<<2048, 256, 0, stream>>>((const float4*)x1, XA, 4.0f, 1, MK, 0u, 262144u);
  expand3<<<2048, 256, 0, stream>>>((const float4*)x2, XB, 1.0f, 0, MK, 262144u, 262144u);
  transpose_bf16<<<dim3(16, 64), 256, 0, stream>>>(x2, VT);
  // S = (4*x1) @ x2^T via 3-term expanded K = 3072
  gemm256<<<dim3(16, 16, 1), 512, 0, stream>>>(XA, XB, S, 4096, 4096, 3072, 48);
  softmax_dropout<<<1024, 256, 0, stream>>>(S, MK, P);
  // O = P @ V: split-K x4 (K=4096, 16 tiles/chunk), then reduce
  gemm256<<<dim3(4, 16, 4), 512, 0, stream>>>(P, VT, PT, 4096, 1024, 4096, 16);
  reduce4<<<4096, 256, 0, stream>>>((const float4*)PT, (float4*)out);
}